// Round 19
// baseline (174.034 us; speedup 1.0000x reference)
//
#include <hip/hip_runtime.h>
#include <hip/hip_bf16.h>

#define N 8192
#define OD 64
#define E_EDGES 262144

#define BM 64                          // rows per gemm block
#define KSPLIT 32
#define KSLICE (N / KSPLIT)            // 256
#define NORM_BLOCKS 2048
#define SCAT_BLOCKS 8192
#define EDGE_ITERS (E_EDGES / (SCAT_BLOCKS * 4))   // 8

typedef __attribute__((ext_vector_type(8))) short bf16x8;
typedef __attribute__((ext_vector_type(4))) float f32x4;

__device__ __forceinline__ unsigned short f2bf(float f) {
    union { float f; unsigned u; } v; v.f = f;
    unsigned r = (v.u + 0x7fffu + ((v.u >> 16) & 1u)) >> 16;  // RNE
    return (unsigned short)r;
}

// pack two f32 -> u32 of 2x bf16 (truncated), 1 VALU op
__device__ __forceinline__ unsigned pack_trunc(unsigned lo, unsigned hi) {
#if defined(__has_builtin) && __has_builtin(__builtin_amdgcn_perm)
    return __builtin_amdgcn_perm(hi, lo, 0x07060302u);  // {hi[3:2], lo[3:2]}
#else
    return (lo >> 16) | (hi & 0xFFFF0000u);
#endif
}

__device__ __forceinline__ void gload16(const void* g, void* l) {
    __builtin_amdgcn_global_load_lds(
        (const __attribute__((address_space(1))) unsigned int*)g,
        (__attribute__((address_space(3))) unsigned int*)l, 16, 0, 0);
}

// ---- K1: norm partials (the 256MB stream) + W transpose-convert + zero y/out ----
// 2048 blocks; w-convert on blocks 0-127, zeroing 128 threads/block — both ~free
// against the norm stream (R8-proven arrangement, ~43-45 us).
__global__ __launch_bounds__(256) void prep_norm_kernel(const float* __restrict__ attn,
                                                        const float* __restrict__ w,
                                                        unsigned short* __restrict__ wt,
                                                        float4* __restrict__ y4,
                                                        float4* __restrict__ out4,
                                                        float* __restrict__ part) {
    const int bid = blockIdx.x, t = threadIdx.x;

    // zero y (131072 f4) + out (131072 f4): 2048 blocks x 128 f4
    if (t < 128) {
        int zi = bid * 128 + t;
        float4 z{0.f, 0.f, 0.f, 0.f};
        if (zi < 131072) y4[zi] = z;
        else out4[zi - 131072] = z;
    }

    // W [N][OD] f32 -> wt [OD][N] bf16 (LDS transpose), blocks 0-127
    if (bid < 128) {
        __shared__ unsigned short lds[64][80];
        const int kb = bid * 64;
        #pragma unroll
        for (int p = 0; p < 4; ++p) {
            int idx = p * 1024 + t * 4;
            int r = idx >> 6, c = idx & 63;
            float4 v = *(const float4*)(&w[(size_t)(kb + r) * OD + c]);
            lds[c + 0][r] = f2bf(v.x);
            lds[c + 1][r] = f2bf(v.y);
            lds[c + 2][r] = f2bf(v.z);
            lds[c + 3][r] = f2bf(v.w);
        }
        __syncthreads();
        const int colx = t >> 2, j0 = (t & 3) * 16;
        #pragma unroll
        for (int u = 0; u < 2; ++u) {
            *(bf16x8*)(wt + (size_t)colx * N + kb + j0 + u * 8) =
                *(const bf16x8*)(&lds[colx][j0 + u * 8]);
        }
    }

    // norm-sq partial over attn (grid-stride, all 2048 blocks) — proven 85% BW
    const float4* a4 = (const float4*)attn;
    const int total = (N * (long)N) / 4;
    float s = 0.f;
    for (long i = (long)bid * 256 + t; i < total; i += (long)NORM_BLOCKS * 256) {
        float4 v = a4[i];
        s += v.x * v.x + v.y * v.y + v.z * v.z + v.w * v.w;
    }
    for (int off = 32; off > 0; off >>= 1) s += __shfl_down(s, off, 64);
    __shared__ float wpart[4];
    int wid = t >> 6;
    if ((t & 63) == 0) wpart[wid] = s;
    __syncthreads();
    if (t == 0) part[bid] = wpart[0] + wpart[1] + wpart[2] + wpart[3];  // plain store
}

// ---- K2: y += x[:,split] @ W[split,:] — R18 byte-identical (session-best gemm) ----
__global__ __launch_bounds__(256) void gemm_kernel(const float* __restrict__ x,
                                                   const unsigned short* __restrict__ wt,
                                                   float* __restrict__ y) {
    __shared__ unsigned short blds[64 * KSLICE];   // 32 KB, XOR-swizzled

    const int t = threadIdx.x;
    const int wv = t >> 6, lane = t & 63;
    const int lrow = lane & 15, g = lane >> 4;
    const int row = blockIdx.x * BM + wv * 16 + lrow;
    const int k0 = blockIdx.y * KSLICE;
    const int key = (lrow & 7) << 3;               // element-space XOR swizzle key

    #pragma unroll
    for (int j = 0; j < 8; ++j) {
        const int idx = j * 256 + t;               // 0..2047
        const int br = idx >> 5;                   // B row 0..63
        const int ch = idx & 31;                   // 16B chunk in row
        gload16(wt + (size_t)br * N + k0 + ((ch ^ (br & 7)) << 3),
                &blds[idx * 8]);
    }
    asm volatile("s_waitcnt vmcnt(0)" ::: "memory");
    __builtin_amdgcn_sched_barrier(0);
    __builtin_amdgcn_s_barrier();                  // the ONLY barrier

    f32x4 acc[4] = {f32x4{0,0,0,0}, f32x4{0,0,0,0}, f32x4{0,0,0,0}, f32x4{0,0,0,0}};
    const float* xp = x + (size_t)row * N + k0 + g * 8;
    uint4 xb[8];
    bf16x8 A[4];

    #define LOADQ(q)                                                  \
        _Pragma("unroll")                                             \
        for (int i = 0; i < 4; ++i) {                                 \
            xb[2*i]   = *(const uint4*)(xp + (q) * 128 + i * 32);     \
            xb[2*i+1] = *(const uint4*)(xp + (q) * 128 + i * 32 + 4); \
        }

    #define PACKQ()                                                   \
        _Pragma("unroll")                                             \
        for (int i = 0; i < 4; ++i) {                                 \
            union { bf16x8 v; unsigned u[4]; } Au;                    \
            Au.u[0] = pack_trunc(xb[2*i].x,   xb[2*i].y);             \
            Au.u[1] = pack_trunc(xb[2*i].z,   xb[2*i].w);             \
            Au.u[2] = pack_trunc(xb[2*i+1].x, xb[2*i+1].y);           \
            Au.u[3] = pack_trunc(xb[2*i+1].z, xb[2*i+1].w);           \
            A[i] = Au.v;                                              \
        }

    #define MFMAQ(q)                                                               \
        _Pragma("unroll")                                                          \
        for (int ks = 0; ks < 4; ++ks) {                                           \
            _Pragma("unroll")                                                      \
            for (int cf = 0; cf < 4; ++cf) {                                       \
                const int ko = (q) * 128 + ks * 32 + g * 8;                        \
                bf16x8 b = *(const bf16x8*)&blds[(cf * 16 + lrow) * KSLICE +       \
                                                 (ko ^ key)];                      \
                acc[cf] = __builtin_amdgcn_mfma_f32_16x16x32_bf16(A[ks], b,        \
                                                                  acc[cf], 0,0,0); \
            }                                                                      \
        }

    LOADQ(0);
    PACKQ(); LOADQ(1); MFMAQ(0);
    PACKQ();           MFMAQ(1);

    // C/D layout: col = lane&15, row = (lane>>4)*4 + i (verified); split-K via atomics
    float* yp = y + ((size_t)blockIdx.x * BM + wv * 16 + g * 4) * OD;
    #pragma unroll
    for (int cf = 0; cf < 4; ++cf) {
        #pragma unroll
        for (int i = 0; i < 4; ++i)
            atomicAdd(&yp[i * OD + cf * 16 + lrow], acc[cf][i]);
    }
    #undef LOADQ
    #undef PACKQ
    #undef MFMAQ
}

// ---- K3: batched edge scatter + norm finalize (+1 block; partials from K1, safe) ----
__global__ __launch_bounds__(256) void scatter_kernel(const float* __restrict__ values,
                                                      const float* __restrict__ attn,
                                                      const int* __restrict__ row,
                                                      const int* __restrict__ col,
                                                      const float* __restrict__ y,
                                                      float* __restrict__ out,
                                                      const float* __restrict__ part,
                                                      float* __restrict__ out_norm) {
    const int t = threadIdx.x;
    if (blockIdx.x == SCAT_BLOCKS) {   // finalize: part[] written by node K1
        float s = 0.f;
        #pragma unroll
        for (int k = 0; k < NORM_BLOCKS / 256; ++k) s += part[k * 256 + t];
        for (int off = 32; off > 0; off >>= 1) s += __shfl_down(s, off, 64);
        __shared__ float wp[4];
        int wid = t >> 6;
        if ((t & 63) == 0) wp[wid] = s;
        __syncthreads();
        if (t == 0) *out_norm = sqrtf(wp[0] + wp[1] + wp[2] + wp[3]);
        return;
    }
    const int bid = blockIdx.x;
    const int lane = t & 63;
    const int w = t >> 6;
    int r8[EDGE_ITERS], c8[EDGE_ITERS];
    float v8[EDGE_ITERS], a8[EDGE_ITERS];
    #pragma unroll
    for (int i = 0; i < EDGE_ITERS; ++i) {       // phase 1: edge meta (independent)
        int e = bid * 4 + w + i * (SCAT_BLOCKS * 4);
        r8[i] = row[e]; c8[i] = col[e]; v8[i] = values[e];
    }
    #pragma unroll
    for (int i = 0; i < EDGE_ITERS; ++i)         // phase 2: 8 gathers in flight
        a8[i] = attn[(size_t)r8[i] * N + c8[i]];
    #pragma unroll
    for (int i = 0; i < EDGE_ITERS; ++i) {       // phase 3: y read (L2) + atomic
        float yv = y[c8[i] * OD + lane];
        atomicAdd(&out[r8[i] * OD + lane], v8[i] * a8[i] * yv);
    }
}

extern "C" void kernel_launch(void* const* d_in, const int* in_sizes, int n_in,
                              void* d_out, int out_size, void* d_ws, size_t ws_size,
                              hipStream_t stream) {
    const float* x      = (const float*)d_in[0];
    const float* attn   = (const float*)d_in[1];
    const float* weight = (const float*)d_in[2];
    const float* values = (const float*)d_in[3];
    const int*   row    = (const int*)d_in[4];
    const int*   col    = (const int*)d_in[5];
    float* out = (float*)d_out;

    char* wsb = (char*)d_ws;
    float*          part = (float*)wsb;                          // 8 KB (2048 f32)
    unsigned short* wt   = (unsigned short*)(wsb + (1u << 20));  // 1 MB
    float*          y    = (float*)(wsb + (2u << 20));           // 2 MB

    prep_norm_kernel<<<NORM_BLOCKS, 256, 0, stream>>>(attn, weight, wt, (float4*)y,
                                                      (float4*)out, part);
    gemm_kernel<<<dim3(N / BM, KSPLIT), 256, 0, stream>>>(x, wt, y);
    scatter_kernel<<<SCAT_BLOCKS + 1, 256, 0, stream>>>(values, attn, row, col, y, out,
                                                        part, out + (size_t)N * OD);
}

// Round 20
// 157.815 us; speedup vs baseline: 1.1028x; 1.1028x over previous
//
#include <hip/hip_runtime.h>
#include <hip/hip_bf16.h>

#define N 8192
#define OD 64
#define E_EDGES 262144

#define BM 64                          // rows per gemm block
#define KSPLIT 32
#define KSLICE (N / KSPLIT)            // 256
#define SCAT_BLOCKS 8192
#define EDGE_ITERS (E_EDGES / (SCAT_BLOCKS * 4))   // 8

typedef __attribute__((ext_vector_type(8))) short bf16x8;
typedef __attribute__((ext_vector_type(4))) float f32x4;

__device__ __forceinline__ unsigned short f2bf(float f) {
    union { float f; unsigned u; } v; v.f = f;
    unsigned r = (v.u + 0x7fffu + ((v.u >> 16) & 1u)) >> 16;  // RNE
    return (unsigned short)r;
}

// pack two f32 -> u32 of 2x bf16 (truncated), 1 VALU op
__device__ __forceinline__ unsigned pack_trunc(unsigned lo, unsigned hi) {
#if defined(__has_builtin) && __has_builtin(__builtin_amdgcn_perm)
    return __builtin_amdgcn_perm(hi, lo, 0x07060302u);  // {hi[3:2], lo[3:2]}
#else
    return (lo >> 16) | (hi & 0xFFFF0000u);
#endif
}

__device__ __forceinline__ void gload16(const void* g, void* l) {
    __builtin_amdgcn_global_load_lds(
        (const __attribute__((address_space(1))) unsigned int*)g,
        (__attribute__((address_space(3))) unsigned int*)l, 16, 0, 0);
}

// ---- K1 (tiny): W [N][OD] f32 -> wt [OD][N] bf16 + zero y/out ----
__global__ __launch_bounds__(256) void prep_kernel(const float* __restrict__ w,
                                                   unsigned short* __restrict__ wt,
                                                   float4* __restrict__ y4,
                                                   float4* __restrict__ out4) {
    const int bid = blockIdx.x, t = threadIdx.x;   // 128 blocks
    const int base = bid * 256 + t;
    float4 z{0.f, 0.f, 0.f, 0.f};
    #pragma unroll
    for (int u = 0; u < 4; ++u) y4[base + u * 32768] = z;
    #pragma unroll
    for (int u = 0; u < 4; ++u) out4[base + u * 32768] = z;

    __shared__ unsigned short lds[64][80];
    const int kb = bid * 64;
    #pragma unroll
    for (int p = 0; p < 4; ++p) {
        int idx = p * 1024 + t * 4;
        int r = idx >> 6, c = idx & 63;
        float4 v = *(const float4*)(&w[(size_t)(kb + r) * OD + c]);
        lds[c + 0][r] = f2bf(v.x);
        lds[c + 1][r] = f2bf(v.y);
        lds[c + 2][r] = f2bf(v.z);
        lds[c + 3][r] = f2bf(v.w);
    }
    __syncthreads();
    const int colx = t >> 2, j0 = (t & 3) * 16;
    #pragma unroll
    for (int u = 0; u < 2; ++u) {
        *(bf16x8*)(wt + (size_t)colx * N + kb + j0 + u * 8) =
            *(const bf16x8*)(&lds[colx][j0 + u * 8]);
    }
}

// ---- K2: y += x[:,split] @ W[split,:] — 32KB B-in-LDS once, high-occupancy x stream ----
// grid (128, 32): 64 rows x K=256 per block. LDS 32 KB -> ~5 blocks/CU (~20 waves/CU).
__global__ __launch_bounds__(256) void gemm_kernel(const float* __restrict__ x,
                                                   const unsigned short* __restrict__ wt,
                                                   float* __restrict__ y) {
    __shared__ unsigned short blds[64 * KSLICE];   // 32 KB, XOR-swizzled

    const int t = threadIdx.x;
    const int wv = t >> 6, lane = t & 63;
    const int lrow = lane & 15, g = lane >> 4;
    const int row = blockIdx.x * BM + wv * 16 + lrow;
    const int k0 = blockIdx.y * KSLICE;
    const int key = (lrow & 7) << 3;               // element-space XOR swizzle key

    // ---- stage B once: 2048 16B-chunks over 256 threads (8 each).
    // LDS dest linear (uniform base + lane*16); source pre-swizzled (rule #21).
    #pragma unroll
    for (int j = 0; j < 8; ++j) {
        const int idx = j * 256 + t;               // 0..2047
        const int br = idx >> 5;                   // B row 0..63
        const int ch = idx & 31;                   // 16B chunk in row (32 per 256-K row)
        gload16(wt + (size_t)br * N + k0 + ((ch ^ (br & 7)) << 3),
                &blds[idx * 8]);
    }
    asm volatile("s_waitcnt vmcnt(0)" ::: "memory");
    __builtin_amdgcn_sched_barrier(0);
    __builtin_amdgcn_s_barrier();                  // the ONLY barrier

    f32x4 acc[4] = {f32x4{0,0,0,0}, f32x4{0,0,0,0}, f32x4{0,0,0,0}, f32x4{0,0,0,0}};
    const float* xp = x + (size_t)row * N + k0 + g * 8;
    uint4 xb[8];
    bf16x8 A[4];

    #define LOADQ(q)                                                  \
        _Pragma("unroll")                                             \
        for (int i = 0; i < 4; ++i) {                                 \
            xb[2*i]   = *(const uint4*)(xp + (q) * 128 + i * 32);     \
            xb[2*i+1] = *(const uint4*)(xp + (q) * 128 + i * 32 + 4); \
        }

    #define PACKQ()                                                   \
        _Pragma("unroll")                                             \
        for (int i = 0; i < 4; ++i) {                                 \
            union { bf16x8 v; unsigned u[4]; } Au;                    \
            Au.u[0] = pack_trunc(xb[2*i].x,   xb[2*i].y);             \
            Au.u[1] = pack_trunc(xb[2*i].z,   xb[2*i].w);             \
            Au.u[2] = pack_trunc(xb[2*i+1].x, xb[2*i+1].y);           \
            Au.u[3] = pack_trunc(xb[2*i+1].z, xb[2*i+1].w);           \
            A[i] = Au.v;                                              \
        }

    #define MFMAQ(q)                                                               \
        _Pragma("unroll")                                                          \
        for (int ks = 0; ks < 4; ++ks) {                                           \
            _Pragma("unroll")                                                      \
            for (int cf = 0; cf < 4; ++cf) {                                       \
                const int ko = (q) * 128 + ks * 32 + g * 8;                        \
                bf16x8 b = *(const bf16x8*)&blds[(cf * 16 + lrow) * KSLICE +       \
                                                 (ko ^ key)];                      \
                acc[cf] = __builtin_amdgcn_mfma_f32_16x16x32_bf16(A[ks], b,        \
                                                                  acc[cf], 0,0,0); \
            }                                                                      \
        }

    LOADQ(0);
    PACKQ(); LOADQ(1); MFMAQ(0);   // quarter q+1 loads fly under quarter q's MFMAs
    PACKQ();           MFMAQ(1);

    // C/D layout: col = lane&15, row = (lane>>4)*4 + i (verified); split-K via atomics
    float* yp = y + ((size_t)blockIdx.x * BM + wv * 16 + g * 4) * OD;
    #pragma unroll
    for (int cf = 0; cf < 4; ++cf) {
        #pragma unroll
        for (int i = 0; i < 4; ++i)
            atomicAdd(&yp[i * OD + cf * 16 + lrow], acc[cf][i]);
    }
    #undef LOADQ
    #undef PACKQ
    #undef MFMAQ
}

// ---- K3: fused scatter (batched) + norm stream ----
__device__ __forceinline__ void do_scatter(const float* __restrict__ values,
                                           const float* __restrict__ attn,
                                           const int* __restrict__ row,
                                           const int* __restrict__ col,
                                           const float* __restrict__ y,
                                           float* __restrict__ out,
                                           int bid, int t) {
    const int lane = t & 63;
    const int w = t >> 6;
    int r8[EDGE_ITERS], c8[EDGE_ITERS];
    float v8[EDGE_ITERS], a8[EDGE_ITERS];
    #pragma unroll
    for (int i = 0; i < EDGE_ITERS; ++i) {
        int e = bid * 4 + w + i * (SCAT_BLOCKS * 4);
        r8[i] = row[e]; c8[i] = col[e]; v8[i] = values[e];
    }
    #pragma unroll
    for (int i = 0; i < EDGE_ITERS; ++i)
        a8[i] = attn[(size_t)r8[i] * N + c8[i]];
    #pragma unroll
    for (int i = 0; i < EDGE_ITERS; ++i) {
        float yv = y[c8[i] * OD + lane];
        atomicAdd(&out[r8[i] * OD + lane], v8[i] * a8[i] * yv);
    }
}

__device__ __forceinline__ float do_norm_part(const float* __restrict__ attn, int bid, int t) {
    const float4* a4 = (const float4*)attn;
    float s = 0.f;
    int i = bid * 256 + t;
    #pragma unroll
    for (int u = 0; u < 8; ++u) {
        float4 v = a4[i + u * (SCAT_BLOCKS * 256)];
        s += v.x * v.x + v.y * v.y + v.z * v.z + v.w * v.w;
    }
    return s;
}

__global__ __launch_bounds__(256) void scatter_norm_kernel(
        const float* __restrict__ values, const float* __restrict__ attn,
        const int* __restrict__ row, const int* __restrict__ col,
        const float* __restrict__ y, float* __restrict__ out,
        float* __restrict__ part) {
    const int bid = blockIdx.x, t = threadIdx.x;
    float s;
    if (bid & 1) {
        s = do_norm_part(attn, bid, t);
        do_scatter(values, attn, row, col, y, out, bid, t);
    } else {
        do_scatter(values, attn, row, col, y, out, bid, t);
        s = do_norm_part(attn, bid, t);
    }
    for (int off = 32; off > 0; off >>= 1) s += __shfl_down(s, off, 64);
    __shared__ float wpart[4];
    int wid = t >> 6;
    if ((t & 63) == 0) wpart[wid] = s;
    __syncthreads();
    if (t == 0) part[bid] = wpart[0] + wpart[1] + wpart[2] + wpart[3];
}

// ---- K4 (tiny): norm = sqrt(sum of 8192 partials) ----
__global__ __launch_bounds__(256) void finalize_kernel(const float* __restrict__ part,
                                                       float* __restrict__ out_norm) {
    float s = 0.f;
    #pragma unroll
    for (int k = 0; k < SCAT_BLOCKS / 256; ++k) s += part[k * 256 + threadIdx.x];
    for (int off = 32; off > 0; off >>= 1) s += __shfl_down(s, off, 64);
    __shared__ float wp[4];
    int wid = threadIdx.x >> 6;
    if ((threadIdx.x & 63) == 0) wp[wid] = s;
    __syncthreads();
    if (threadIdx.x == 0) *out_norm = sqrtf(wp[0] + wp[1] + wp[2] + wp[3]);
}

extern "C" void kernel_launch(void* const* d_in, const int* in_sizes, int n_in,
                              void* d_out, int out_size, void* d_ws, size_t ws_size,
                              hipStream_t stream) {
    const float* x      = (const float*)d_in[0];
    const float* attn   = (const float*)d_in[1];
    const float* weight = (const float*)d_in[2];
    const float* values = (const float*)d_in[3];
    const int*   row    = (const int*)d_in[4];
    const int*   col    = (const int*)d_in[5];
    float* out = (float*)d_out;

    char* wsb = (char*)d_ws;
    float*          part = (float*)wsb;                          // 32 KB
    unsigned short* wt   = (unsigned short*)(wsb + (1u << 20));  // 1 MB
    float*          y    = (float*)(wsb + (2u << 20));           // 2 MB

    prep_kernel<<<128, 256, 0, stream>>>(weight, wt, (float4*)y, (float4*)out);
    gemm_kernel<<<dim3(N / BM, KSPLIT), 256, 0, stream>>>(x, wt, y);
    scatter_norm_kernel<<<SCAT_BLOCKS, 256, 0, stream>>>(values, attn, row, col, y, out, part);
    finalize_kernel<<<1, 256, 0, stream>>>(part, out + (size_t)N * OD);
}